// Round 6
// baseline (7049.704 us; speedup 1.0000x reference)
//
#include <hip/hip_runtime.h>
#include <math.h>

// LSTM: L=7, H=49, B=1024, T=512, I=7, O=7. fp32 in/out.
//
// Round 6: cross-layer pipelined persistent kernel, ring sized for real ws.
//  - R5's pipeline never ran (WS_NEEDED 763MB > ws_size; fallback ran).
//    This round: wraparound rings, NB=6 blocks x 8 steps per boundary
//    (61.4 MB total) + producer backpressure via consumer acks.
//  - 448 WGs (7 layers x 64 groups), 448 thr (7 waves), 16 samples/WG.
//    2 WGs/CU co-resident (LDS 33KB, launch_bounds(448,4) -> <=128 VGPR)
//    -> all WGs resident -> pipeline flags can't deadlock.
//  - Boundary l: pub[l][grp] = #blocks published (producer l, release/agent);
//    ack[l][grp] = #blocks consumed (consumer l+1, relaxed/agent — its reads
//    are complete before the ack: values consumed into LDS a step earlier,
//    barrier-ordered). Producer writes block k only when ack >= k-NB+1.
//  - FC fused into layer 6: h_{t-1} sits in A-planes k=0..48 at step t, so
//    wave 6 (1 gate tile only) adds 6 MFMAs vs fcw frags (B zero for k>=49,
//    so the x region at k>=52 can't pollute) and stores out[t-1] directly.
//    Epilogue computes out[511]. No layer-6 ring, no h buffer, no FC kernel.
//  - Numerics: 3-pass bf16 hi/lo split MFMA + fp32 EW (proven R3-R5).

constexpr int TT = 512;
constexpr int BB = 1024;
constexpr int HH = 49;
constexpr int GG = 196;

constexpr int    NB          = 6;                  // ring depth (blocks)
constexpr int    RBLK        = 416;                // floats per block (8x52)
constexpr size_t R_SAMP      = (size_t)NB * RBLK;  // 2496 floats
constexpr size_t R_LAYER     = 1024ull * R_SAMP;
constexpr size_t RING_FLOATS = 6ull * R_LAYER;     // boundaries 0..5
constexpr size_t FLAG_INTS   = 2ull * 6 * 64 * 32; // pub + ack, 128B strided
constexpr size_t WS_NEEDED   = RING_FLOATS * 4 + FLAG_INTS * 4;

typedef __attribute__((ext_vector_type(8))) short short8;
typedef __attribute__((ext_vector_type(4))) short short4v;
typedef __attribute__((ext_vector_type(4))) float f32x4;

__device__ __forceinline__ float sigmoidf_(float x) {
    return 1.0f / (1.0f + __expf(-x));
}
__device__ __forceinline__ float tanhf_(float x) {
    return 1.0f - 2.0f / (1.0f + __expf(2.0f * x));
}

__device__ __forceinline__ void bf16split(float x, short& hi, short& lo) {
    unsigned u = __float_as_uint(x);
    unsigned r = u + 0x7FFFu + ((u >> 16) & 1u);
    hi = (short)(r >> 16);
    float fhi = __uint_as_float(r & 0xFFFF0000u);
    float rem = x - fhi;
    unsigned u2 = __float_as_uint(rem);
    unsigned r2 = u2 + 0x7FFFu + ((u2 >> 16) & 1u);
    lo = (short)(r2 >> 16);
}

// fragment-order element address (2B units) of A[m][k], m<16, k<128
__device__ __forceinline__ int addr2B(int m, int k) {
    return (k >> 5) * 512 + ((k >> 3) & 3) * 128 + m * 8 + (k & 7);
}

#define WGBAR() asm volatile("s_waitcnt lgkmcnt(0)\n\ts_barrier" ::: "memory")
#define VMDRAIN() asm volatile("s_waitcnt vmcnt(0)" ::: "memory")

__global__ void zero_flags(int* f, int n) {
    int i = blockIdx.x * 256 + threadIdx.x;
    if (i < n) f[i] = 0;
}

__global__ __launch_bounds__(448, 4)
void lstm_pipe(const float* __restrict__ xin,    // [B,T,7]
               float* __restrict__ ring,         // [6][1024][NB][8][52]
               int* __restrict__ flags,          // pub[6][64][32] ack[6][64][32]
               const float* __restrict__ Wih0,   // [196,7]
               const float* __restrict__ Wihr,   // [6,196,49]
               const float* __restrict__ Whh,    // [7,196,49]
               const float* __restrict__ bih,    // [7,196]
               const float* __restrict__ bhh,    // [7,196]
               const float* __restrict__ fcw,    // [7,49]
               const float* __restrict__ fcb,    // [7]
               float* __restrict__ outp)         // [B,T,7]
{
    __shared__ short Ahi[2][2048];               // [parity][frag order]
    __shared__ short Alo[2][2048];
    __shared__ float preT[13 * 16 * 20];         // [tile][sample m][n' pad20]

    const int tid  = threadIdx.x;
    const int wave = tid >> 6;
    const int lane = tid & 63;
    const int quad = lane >> 4;
    const int lrow = lane & 15;

    const int l   = blockIdx.x >> 6;             // layer 0..6
    const int grp = blockIdx.x & 63;
    const int b0  = grp << 4;

    const int DIN  = (l == 0) ? 7 : 49;
    const int KSRT = (l == 0) ? 2 : 4;
    const float* Wih = (l == 0) ? Wih0 : (Wihr + (size_t)(l - 1) * GG * HH);
    const float* Whl = Whh + (size_t)l * GG * HH;
    const float* bi  = bih + (size_t)l * GG;
    const float* bh  = bhh + (size_t)l * GG;

    const float* rin  = ring + (size_t)(l - 1) * R_LAYER;   // l>0
    float*       rout = ring + (size_t)l * R_LAYER;         // l<6
    int* pubf = flags;
    int* ackf = flags + 6 * 64 * 32;
    int* pub_in  = pubf + ((size_t)(l - 1) * 64 + grp) * 32;   // l>0 reads
    int* pub_out = pubf + ((size_t)l * 64 + grp) * 32;         // l<6 writes
    int* ack_in  = ackf + ((size_t)(l - 1) * 64 + grp) * 32;   // l>0 writes
    int* ack_out = ackf + ((size_t)l * 64 + grp) * 32;         // l<6 reads

    const int ntiles = (wave < 6) ? 2 : 1;
    const int tA = (wave < 6) ? wave : 12;
    const int tB = wave + 6;

    // ---- B fragments (hi/lo) + bias in VGPRs -----------------------------
    short8 BH[2][4], BL[2][4];
    float  biasv[2];
    #pragma unroll
    for (int ti = 0; ti < 2; ++ti) {
        const int  nt    = ti ? tB : tA;
        const bool valid = (ti < ntiles) && (nt < 13);
        const int  np    = nt * 16 + lrow;       // permuted row r' = 4j+g
        const int  j     = np >> 2;
        const int  g     = np & 3;
        const bool jb    = valid && (j < HH);
        biasv[ti] = jb ? (bi[g * HH + j] + bh[g * HH + j]) : 0.0f;
        #pragma unroll
        for (int ks = 0; ks < 4; ++ks) {
            #pragma unroll
            for (int jj = 0; jj < 8; ++jj) {
                const int k = ks * 32 + quad * 8 + jj;
                float wv = 0.0f;
                if (jb) {
                    const int r = g * HH + j;
                    if (k < HH)                       wv = Whl[r * HH + k];
                    else if (k >= 52 && k < 52 + DIN) wv = Wih[r * DIN + (k - 52)];
                }
                short h_, l_;
                bf16split(wv, h_, l_);
                BH[ti][ks][jj] = h_;
                BL[ti][ks][jj] = l_;
            }
        }
    }

    // ---- FC fragments (layer 6, wave 6 only uses them) -------------------
    short8 FH[2], FL[2];
    float  fcbias = 0.0f;
    {
        const int o = lrow;
        fcbias = (l == 6 && o < 7) ? fcb[o] : 0.0f;
        #pragma unroll
        for (int ks = 0; ks < 2; ++ks) {
            #pragma unroll
            for (int jj = 0; jj < 8; ++jj) {
                const int k = ks * 32 + quad * 8 + jj;
                float wv = 0.0f;
                if (l == 6 && o < 7 && k < HH) wv = fcw[o * HH + k];
                short h_, l_;
                bf16split(wv, h_, l_);
                FH[ks][jj] = h_;
                FL[ks][jj] = l_;
            }
        }
    }

    // ---- EW cells: lane owns (tile, j = 4*tile+quad, sample = lrow) ------
    const int  j0 = 4 * tA + quad;
    const int  j1 = 4 * tB + quad;
    const bool v0 = (j0 < HH);
    const bool v1 = (wave < 6);
    const int  ah0 = addr2B(lrow, j0 < HH ? j0 : 0);
    const int  ah1 = addr2B(lrow, v1 ? j1 : 0);
    float* rc0 = rout + (size_t)(b0 + lrow) * R_SAMP + (j0 < HH ? j0 : 0);
    float* rc1 = rout + (size_t)(b0 + lrow) * R_SAMP + (v1 ? j1 : 0);
    float cc0 = 0.0f, cc1 = 0.0f;

    // ---- loader role -----------------------------------------------------
    bool is_ld;
    int  a_st;
    const float* gb;
    if (l == 0) {
        is_ld = (tid < 112);                     // 16 samples x 7 cols
        const int m = tid / 7, c = tid - (tid / 7) * 7;
        a_st = addr2B(m & 15, 52 + c);
        gb   = xin + ((size_t)(b0 + (m & 15)) * TT) * 7 + c;
    } else {
        is_ld = (tid < 208);                     // 16 samples x 13 quads
        const int m = tid / 13, q = tid - (tid / 13) * 13;
        a_st = addr2B(m & 15, 52 + 4 * q);
        gb   = rin + (size_t)(b0 + (m & 15)) * R_SAMP + 4 * q;
    }

    // ---- init A planes (h0 = 0, pads stay 0) -----------------------------
    for (int i = tid; i < 2048; i += 448) {
        ((unsigned*)Ahi)[i] = 0u;
        ((unsigned*)Alo)[i] = 0u;
    }
    __syncthreads();

    if (l > 0) {                                 // wait for block 0
        if (tid == 0) {
            while (__hip_atomic_load(pub_in, __ATOMIC_ACQUIRE,
                                     __HIP_MEMORY_SCOPE_AGENT) < 1)
                __builtin_amdgcn_s_sleep(8);
        }
        __syncthreads();
        __builtin_amdgcn_fence(__ATOMIC_ACQUIRE, "agent");
    }

    // xr0 = even-step x, xr1 = odd-step x (both in block 0 initially)
    float4 xr0 = {0, 0, 0, 0}, xr1 = {0, 0, 0, 0};
    if (is_ld) {
        if (l == 0) { xr0.x = gb[0]; xr1.x = gb[7]; }
        else        { xr0 = *(const float4*)gb; xr1 = *(const float4*)(gb + 52); }
    }

    // stage x_0 -> A[0]
    if (is_ld) {
        if (l == 0) {
            short h_, l_;
            bf16split(xr0.x, h_, l_);
            Ahi[0][a_st] = h_; Alo[0][a_st] = l_;
        } else {
            short h0,l0_,h1,l1_,h2,l2_,h3,l3_;
            bf16split(xr0.x,h0,l0_); bf16split(xr0.y,h1,l1_);
            bf16split(xr0.z,h2,l2_); bf16split(xr0.w,h3,l3_);
            short4v vh = {h0,h1,h2,h3}, vl = {l0_,l1_,l2_,l3_};
            *(short4v*)&Ahi[0][a_st] = vh;
            *(short4v*)&Alo[0][a_st] = vl;
        }
    }
    __syncthreads();

    // ---- scan ------------------------------------------------------------
    for (int t = 0; t < TT; ++t) {
        const int p   = t & 1;
        const int tb  = t & 7;
        const int blk = t >> 3;

        // producer: drain block blk-1 stores, then publish
        if (l < 6) {
            if (tb == 2) VMDRAIN();
            if (tb == 3 && blk >= 1 && tid == 0)
                __hip_atomic_store(pub_out, blk, __ATOMIC_RELEASE,
                                   __HIP_MEMORY_SCOPE_AGENT);
        }
        // consumer: ack blocks 0..blk-1 consumed (reads provably complete)
        if (l > 0 && tb == 0 && blk >= 1 && tid == 0)
            __hip_atomic_store(ack_in, blk, __ATOMIC_RELAXED,
                               __HIP_MEMORY_SCOPE_AGENT);
        // producer backpressure: block blk reusable only after consumer ack
        if (l < 6 && tb == 0 && blk >= NB) {
            if (tid == 0) {
                const int need = blk - NB + 1;
                while (__hip_atomic_load(ack_out, __ATOMIC_ACQUIRE,
                                         __HIP_MEMORY_SCOPE_AGENT) < need)
                    __builtin_amdgcn_s_sleep(8);
            }
            WGBAR();
        }
        // consumer gate before prefetch crosses into a new block
        if (l > 0 && tb == 6 && (t + 2) < TT) {
            const int want = ((t + 2) >> 3) + 1;
            if (tid == 0) {
                while (__hip_atomic_load(pub_in, __ATOMIC_ACQUIRE,
                                         __HIP_MEMORY_SCOPE_AGENT) < want)
                    __builtin_amdgcn_s_sleep(8);
            }
            WGBAR();
            __builtin_amdgcn_fence(__ATOMIC_ACQUIRE, "agent");
        }

        // prefetch x_{t+2}
        float4 xnew = {0, 0, 0, 0};
        const bool ldnow = is_ld && (t + 2) < TT;
        if (ldnow) {
            if (l == 0) xnew.x = gb[(size_t)(t + 2) * 7];
            else {
                const int offn = (((t + 2) >> 3) % NB) * RBLK + ((t + 2) & 7) * 52;
                xnew = *(const float4*)(gb + offn);
            }
        }

        // A fragments (parity p), conflict-free b128
        short8 AH[4], AL[4];
        #pragma unroll
        for (int ks = 0; ks < 4; ++ks) {
            if (ks < KSRT) {
                AH[ks] = *(const short8*)&Ahi[p][ks * 512 + lane * 8];
                AL[ks] = *(const short8*)&Alo[p][ks * 512 + lane * 8];
            }
        }

        // MFMA: tile A (all waves) + tile B (waves 0..5)
        f32x4 C0 = {biasv[0], biasv[0], biasv[0], biasv[0]};
        #pragma unroll
        for (int ks = 0; ks < 4; ++ks) {
            if (ks < KSRT) {
                C0 = __builtin_amdgcn_mfma_f32_16x16x32_bf16(AH[ks], BH[0][ks], C0, 0, 0, 0);
                C0 = __builtin_amdgcn_mfma_f32_16x16x32_bf16(AL[ks], BH[0][ks], C0, 0, 0, 0);
                C0 = __builtin_amdgcn_mfma_f32_16x16x32_bf16(AH[ks], BL[0][ks], C0, 0, 0, 0);
            }
        }
        #pragma unroll
        for (int r = 0; r < 4; ++r)
            preT[(tA * 16 + 4 * quad + r) * 20 + lrow] = C0[r];

        if (wave < 6) {
            f32x4 C1 = {biasv[1], biasv[1], biasv[1], biasv[1]};
            #pragma unroll
            for (int ks = 0; ks < 4; ++ks) {
                if (ks < KSRT) {
                    C1 = __builtin_amdgcn_mfma_f32_16x16x32_bf16(AH[ks], BH[1][ks], C1, 0, 0, 0);
                    C1 = __builtin_amdgcn_mfma_f32_16x16x32_bf16(AL[ks], BH[1][ks], C1, 0, 0, 0);
                    C1 = __builtin_amdgcn_mfma_f32_16x16x32_bf16(AH[ks], BL[1][ks], C1, 0, 0, 0);
                }
            }
            #pragma unroll
            for (int r = 0; r < 4; ++r)
                preT[(tB * 16 + 4 * quad + r) * 20 + lrow] = C1[r];
        }

        // fused FC (layer 6, wave 6): out[t-1] from h_{t-1} in A[p] k=0..48
        if (l == 6 && wave == 6 && t >= 1) {
            f32x4 C = {fcbias, fcbias, fcbias, fcbias};
            C = __builtin_amdgcn_mfma_f32_16x16x32_bf16(AH[0], FH[0], C, 0, 0, 0);
            C = __builtin_amdgcn_mfma_f32_16x16x32_bf16(AL[0], FH[0], C, 0, 0, 0);
            C = __builtin_amdgcn_mfma_f32_16x16x32_bf16(AH[0], FL[0], C, 0, 0, 0);
            C = __builtin_amdgcn_mfma_f32_16x16x32_bf16(AH[1], FH[1], C, 0, 0, 0);
            C = __builtin_amdgcn_mfma_f32_16x16x32_bf16(AL[1], FH[1], C, 0, 0, 0);
            C = __builtin_amdgcn_mfma_f32_16x16x32_bf16(AH[1], FL[1], C, 0, 0, 0);
            if (lrow < 7) {
                #pragma unroll
                for (int r = 0; r < 4; ++r) {
                    const int s = quad * 4 + r;
                    outp[((size_t)(b0 + s) * TT + (t - 1)) * 7 + lrow] = C[r];
                }
            }
        }

        // EW (wave-local preT): cell update, stage h into A[p^1], ring store
        const int offc = (blk % NB) * RBLK + tb * 52;
        if (v0) {
            const f32x4 gt = *(const f32x4*)&preT[(tA * 16 + lrow) * 20 + 4 * quad];
            const float i_ = sigmoidf_(gt.x);
            const float f_ = sigmoidf_(gt.y);
            const float g_ = tanhf_(gt.z);
            const float o_ = sigmoidf_(gt.w);
            cc0 = f_ * cc0 + i_ * g_;
            const float hv = o_ * tanhf_(cc0);
            short hh, hl;
            bf16split(hv, hh, hl);
            Ahi[p ^ 1][ah0] = hh;
            Alo[p ^ 1][ah0] = hl;
            if (l < 6) rc0[offc] = hv;
        }
        if (v1) {
            const f32x4 gt = *(const f32x4*)&preT[(tB * 16 + lrow) * 20 + 4 * quad];
            const float i_ = sigmoidf_(gt.x);
            const float f_ = sigmoidf_(gt.y);
            const float g_ = tanhf_(gt.z);
            const float o_ = sigmoidf_(gt.w);
            cc1 = f_ * cc1 + i_ * g_;
            const float hv = o_ * tanhf_(cc1);
            short hh, hl;
            bf16split(hv, hh, hl);
            Ahi[p ^ 1][ah1] = hh;
            Alo[p ^ 1][ah1] = hl;
            if (l < 6) rc1[offc] = hv;
        }

        // stage x_{t+1} -> A[p^1]
        if (is_ld && (t + 1) < TT) {
            const float4 xv = ((t + 1) & 1) ? xr1 : xr0;
            if (l == 0) {
                short h_, l_;
                bf16split(xv.x, h_, l_);
                Ahi[p ^ 1][a_st] = h_; Alo[p ^ 1][a_st] = l_;
            } else {
                short h0,l0_,h1,l1_,h2,l2_,h3,l3_;
                bf16split(xv.x,h0,l0_); bf16split(xv.y,h1,l1_);
                bf16split(xv.z,h2,l2_); bf16split(xv.w,h3,l3_);
                short4v vh = {h0,h1,h2,h3}, vl = {l0_,l1_,l2_,l3_};
                *(short4v*)&Ahi[p ^ 1][a_st] = vh;
                *(short4v*)&Alo[p ^ 1][a_st] = vl;
            }
        }
        if (ldnow) { if (t & 1) xr1 = xnew; else xr0 = xnew; }

        WGBAR();
    }

    // epilogue: out[511] (h_511 staged into A[0] at t=511)
    if (l == 6 && wave == 6) {
        short8 eh0 = *(const short8*)&Ahi[0][0 * 512 + lane * 8];
        short8 el0 = *(const short8*)&Alo[0][0 * 512 + lane * 8];
        short8 eh1 = *(const short8*)&Ahi[0][1 * 512 + lane * 8];
        short8 el1 = *(const short8*)&Alo[0][1 * 512 + lane * 8];
        f32x4 C = {fcbias, fcbias, fcbias, fcbias};
        C = __builtin_amdgcn_mfma_f32_16x16x32_bf16(eh0, FH[0], C, 0, 0, 0);
        C = __builtin_amdgcn_mfma_f32_16x16x32_bf16(el0, FH[0], C, 0, 0, 0);
        C = __builtin_amdgcn_mfma_f32_16x16x32_bf16(eh0, FL[0], C, 0, 0, 0);
        C = __builtin_amdgcn_mfma_f32_16x16x32_bf16(eh1, FH[1], C, 0, 0, 0);
        C = __builtin_amdgcn_mfma_f32_16x16x32_bf16(el1, FH[1], C, 0, 0, 0);
        C = __builtin_amdgcn_mfma_f32_16x16x32_bf16(eh1, FL[1], C, 0, 0, 0);
        if (lrow < 7) {
            #pragma unroll
            for (int r = 0; r < 4; ++r) {
                const int s = quad * 4 + r;
                outp[((size_t)(b0 + s) * TT + (TT - 1)) * 7 + lrow] = C[r];
            }
        }
    }
    // producer completion: publish final block
    if (l < 6) {
        VMDRAIN();
        __syncthreads();
        if (tid == 0)
            __hip_atomic_store(pub_out, 64, __ATOMIC_RELEASE,
                               __HIP_MEMORY_SCOPE_AGENT);
    }
}

// ======================= fallback path (R5, proven) =========================

template<int DIN>
__global__ __launch_bounds__(448)
void lstm_fb(const float* xin, float* hout,
             const float* __restrict__ Wih, const float* __restrict__ Whh,
             const float* __restrict__ bihp, const float* __restrict__ bhhp)
{
    constexpr int XO = 52;
    constexpr int KTOT = XO + DIN;
    constexpr int KSTEPS = (KTOT + 31) / 32;
    __shared__ short Ahi[2][KSTEPS * 512];
    __shared__ short Alo[2][KSTEPS * 512];
    __shared__ float preT[13 * 64];

    const int tid = threadIdx.x, wave = tid >> 6, lane = tid & 63;
    const int quad = lane >> 4, lrow = lane & 15;
    const int b0 = blockIdx.x * 4;
    const int ntiles = (wave < 6) ? 2 : 1;
    const int tileA = (wave < 6) ? wave : 12;
    const int tileB = wave + 6;

    short8 BH[2][KSTEPS], BL[2][KSTEPS];
    float biasv[2];
    #pragma unroll
    for (int ti = 0; ti < 2; ++ti) {
        const int nt = ti ? tileB : tileA;
        const bool valid = (ti < ntiles);
        const int np = nt * 16 + lrow, j = np >> 2, g = np & 3;
        biasv[ti] = (valid && j < HH) ? (bihp[g*HH+j] + bhhp[g*HH+j]) : 0.0f;
        #pragma unroll
        for (int ks = 0; ks < KSTEPS; ++ks)
            #pragma unroll
            for (int jj = 0; jj < 8; ++jj) {
                const int k = ks * 32 + quad * 8 + jj;
                float wv = 0.0f;
                if (valid && j < HH) {
                    const int r = g * HH + j;
                    if (k < HH) wv = Whh[r * HH + k];
                    else if (k >= XO && k < KTOT) wv = Wih[r * DIN + (k - XO)];
                }
                short h_, l_; bf16split(wv, h_, l_);
                BH[ti][ks][jj] = h_; BL[ti][ks][jj] = l_;
            }
    }

    const int ec = lane & 15, ew_jj = ec >> 2, ew_m = ec & 3, ew_ti = lane >> 4;
    const bool is_ew = (lane < 32) && (ew_ti < ntiles);
    const int ew_nt = ew_ti ? tileB : tileA;
    const int ew_j = 4 * ew_nt + ew_jj;
    const bool ew_ok = is_ew && (ew_j < HH);
    const int pa0 = (ew_nt*16 + 4*ew_jj + 0)*4 + ew_m;
    const int pa1 = (ew_nt*16 + 4*ew_jj + 1)*4 + ew_m;
    const int pa2 = (ew_nt*16 + 4*ew_jj + 2)*4 + ew_m;
    const int pa3 = (ew_nt*16 + 4*ew_jj + 3)*4 + ew_m;
    const int ew_ah = addr2B(ew_m, ew_ok ? ew_j : 0);
    float cc = 0.0f;

    const bool is_loader = (tid < 4 * DIN);
    const int ld_m = is_loader ? (tid & 3) : 0, ld_k = is_loader ? (tid >> 2) : 0;
    const int xaddr = addr2B(ld_m, XO + ld_k);
    const size_t xbase = ((size_t)(b0 + ld_m) * TT) * DIN + ld_k;
    float* houtp = hout + ((size_t)(b0 + ew_m) * TT) * HH + (ew_ok ? ew_j : 0);

    for (int i = tid; i < KSTEPS * 512; i += 448) {
        ((unsigned*)Ahi)[i] = 0u; ((unsigned*)Alo)[i] = 0u;
    }
    __syncthreads();
    if (is_loader) {
        short h_, l_; bf16split(xin[xbase], h_, l_);
        Ahi[0][xaddr] = h_; Alo[0][xaddr] = l_;
    }
    __syncthreads();

    for (int t = 0; t < TT; ++t) {
        const int p = t & 1;
        float xnext = 0.0f;
        if (is_loader && (t + 1 < TT)) xnext = xin[xbase + (size_t)(t+1) * DIN];

        short8 AH[KSTEPS], AL[KSTEPS];
        #pragma unroll
        for (int ks = 0; ks < KSTEPS; ++ks) {
            AH[ks] = *(const short8*)&Ahi[p][ks * 512 + lane * 8];
            AL[ks] = *(const short8*)&Alo[p][ks * 512 + lane * 8];
        }
        #pragma unroll
        for (int ti = 0; ti < 2; ++ti) {
            f32x4 C = {biasv[ti], biasv[ti], biasv[ti], biasv[ti]};
            #pragma unroll
            for (int ks = 0; ks < KSTEPS; ++ks) {
                C = __builtin_amdgcn_mfma_f32_16x16x32_bf16(AH[ks], BH[ti][ks], C, 0, 0, 0);
                C = __builtin_amdgcn_mfma_f32_16x16x32_bf16(AL[ks], BH[ti][ks], C, 0, 0, 0);
                C = __builtin_amdgcn_mfma_f32_16x16x32_bf16(AH[ks], BL[ti][ks], C, 0, 0, 0);
            }
            if (ti < ntiles && lane < 16) {
                const int nt = ti ? tileB : tileA;
                *(f32x4*)&preT[(nt * 16 + lrow) * 4] = C;
            }
        }
        if (is_ew) {
            const float i_ = sigmoidf_(preT[pa0]);
            const float f_ = sigmoidf_(preT[pa1]);
            const float g_ = tanhf_(preT[pa2]);
            const float o_ = sigmoidf_(preT[pa3]);
            cc = f_ * cc + i_ * g_;
            const float hv = o_ * tanhf_(cc);
            if (ew_ok) {
                short hh, hl; bf16split(hv, hh, hl);
                Ahi[p ^ 1][ew_ah] = hh; Alo[p ^ 1][ew_ah] = hl;
                houtp[(size_t)t * HH] = hv;
            }
        }
        if (is_loader && (t + 1 < TT)) {
            short h_, l_; bf16split(xnext, h_, l_);
            Ahi[p ^ 1][xaddr] = h_; Alo[p ^ 1][xaddr] = l_;
        }
        __syncthreads();
    }
}

__global__ __launch_bounds__(256)
void fc_fb(const float* __restrict__ hbuf, const float* __restrict__ fcw,
           const float* __restrict__ fcb, float* __restrict__ outp)
{
    constexpr int HP = 52;
    __shared__ float w[7][HP];
    __shared__ float bsh[8];
    const int tid = threadIdx.x;
    for (int i = tid; i < 7 * HP; i += 256) {
        const int o = i / HP, k = i - o * HP;
        w[o][k] = (k < HH) ? fcw[o * HH + k] : 0.0f;
    }
    if (tid < 7) bsh[tid] = fcb[tid];
    __syncthreads();
    const size_t i = (size_t)blockIdx.x * 256 + tid;
    float acc[7];
    #pragma unroll
    for (int j = 0; j < 7; ++j) acc[j] = bsh[j];
    const float* hp = hbuf + i * HH;
    #pragma unroll
    for (int k = 0; k < HH; ++k) {
        const float hv = hp[k];
        #pragma unroll
        for (int j = 0; j < 7; ++j) acc[j] = fmaf(hv, w[j][k], acc[j]);
    }
    #pragma unroll
    for (int j = 0; j < 7; ++j) outp[i * 7 + j] = acc[j];
}

extern "C" void kernel_launch(void* const* d_in, const int* in_sizes, int n_in,
                              void* d_out, int out_size, void* d_ws, size_t ws_size,
                              hipStream_t stream)
{
    const float* x    = (const float*)d_in[0];
    const float* Wih0 = (const float*)d_in[1];
    const float* Wihr = (const float*)d_in[2];
    const float* Whh  = (const float*)d_in[3];
    const float* bih  = (const float*)d_in[4];
    const float* bhh  = (const float*)d_in[5];
    const float* fcw  = (const float*)d_in[6];
    const float* fcb  = (const float*)d_in[7];
    float* outp = (float*)d_out;

    if (ws_size >= WS_NEEDED) {
        float* ring  = (float*)d_ws;
        int*   flags = (int*)((char*)d_ws + RING_FLOATS * 4);
        zero_flags<<<(int)((FLAG_INTS + 255) / 256), 256, 0, stream>>>(
            flags, (int)FLAG_INTS);
        lstm_pipe<<<448, 448, 0, stream>>>(x, ring, flags, Wih0, Wihr,
                                           Whh, bih, bhh, fcw, fcb, outp);
    } else {
        float* hbuf = (float*)d_ws;   // [B,T,49]
        lstm_fb<7><<<BB / 4, 448, 0, stream>>>(x, hbuf, Wih0, Whh, bih, bhh);
        for (int l = 1; l < 7; ++l) {
            lstm_fb<49><<<BB / 4, 448, 0, stream>>>(
                hbuf, hbuf,
                Wihr + (size_t)(l - 1) * GG * HH,
                Whh  + (size_t)l * GG * HH,
                bih  + (size_t)l * GG,
                bhh  + (size_t)l * GG);
        }
        fc_fb<<<(BB * TT) / 256, 256, 0, stream>>>(hbuf, fcw, fcb, outp);
    }
}

// Round 8
// 4472.409 us; speedup vs baseline: 1.5763x; 1.5763x over previous
//
#include <hip/hip_runtime.h>
#include <math.h>

// LSTM: L=7, H=49, B=1024, T=512, I=7, O=7. fp32 in/out.
//
// Round 8: R7 design (in-register EW, no preT) with a SAFE x loader.
//  R7 crashed: float4 loads at row stride 49/7 floats are only 4B-aligned ->
//  compiler emitted global_load_dwordx4 assuming 16B (UB from the cast) ->
//  GPU memory fault (+12B OOB at the tail quad). Fix: per-element guarded
//  scalar loads (exec-masked, in-bounds, alignment-free). Design unchanged:
//  - Per-layer scan: 256 WGs x 448 thr, M=4 samples/WG, 13 gate-interleaved
//    N-tiles (r'=4j+gate), wave w owns tiles {w, w+6} (wave6: {12} + loader),
//    bias via MFMA C-init, 3-pass bf16 hi/lo split, A planes double-buffered
//    by parity, lgkm-only barrier per step.
//  - EW in MFMA D-layout: lane = gate g=lane&3 of cell j=tile*4+((lane&15)>>2),
//    samples m=quad*4+r. Branchless sigma/tanh (tanh=2*sig(2x)-1 via per-lane
//    consts); 3 DPP quad_perm broadcasts deliver (i,f,g~,o); c per-lane
//    (redundant x4/quad, consistent); cndmask tree picks own-sample h;
//    2 ds_write_b16 stage h straight into A[p^1]. preT deleted.
//  - Garbage D-rows m=4..15 stay bounded (x rows zero, sigma/tanh saturate).

constexpr int TT = 512;
constexpr int BB = 1024;
constexpr int HH = 49;
constexpr int GG = 196;

typedef __attribute__((ext_vector_type(8))) short short8;
typedef __attribute__((ext_vector_type(4))) short short4v;
typedef __attribute__((ext_vector_type(4))) float f32x4;

__device__ __forceinline__ float fsig(float x) {
    return __builtin_amdgcn_rcpf(1.0f + __expf(-x));
}

__device__ __forceinline__ void bf16split(float x, short& hi, short& lo) {
    unsigned u = __float_as_uint(x);
    unsigned r = u + 0x7FFFu + ((u >> 16) & 1u);
    hi = (short)(r >> 16);
    float fhi = __uint_as_float(r & 0xFFFF0000u);
    float rem = x - fhi;
    unsigned u2 = __float_as_uint(rem);
    unsigned r2 = u2 + 0x7FFFu + ((u2 >> 16) & 1u);
    lo = (short)(r2 >> 16);
}

// fragment-order element address (2B units) of A[m][k], m<16, k<128
__device__ __forceinline__ int addr2B(int m, int k) {
    return (k >> 5) * 512 + ((k >> 3) & 3) * 128 + m * 8 + (k & 7);
}

// quad_perm broadcast: every lane gets element CTRL-selected from its 4-lane quad
template<int CTRL>
__device__ __forceinline__ float qbcast(float v) {
    int s = __builtin_amdgcn_update_dpp(0, __float_as_int(v), CTRL, 0xF, 0xF, true);
    return __int_as_float(s);
}

#define WGBAR() asm volatile("s_waitcnt lgkmcnt(0)\n\ts_barrier" ::: "memory")

template<int DIN>
__global__ __launch_bounds__(448, 2)
void lstm_ql(const float* __restrict__ xin,   // [B,T,DIN]
             float* __restrict__ hout,        // [B,T,49]
             const float* __restrict__ Wih,   // [196,DIN]
             const float* __restrict__ Whh,   // [196,49]
             const float* __restrict__ bih,   // [196]
             const float* __restrict__ bhh)   // [196]
{
    constexpr int XO      = 52;                // x offset in k-space
    constexpr int KTOT    = XO + DIN;          // 59 or 101
    constexpr int KSTEPS  = (KTOT + 31) / 32;  // 2 or 4
    constexpr int QN      = (DIN + 3) / 4;     // k-quads per x row: 2 or 13
    constexpr int NL      = 4 * QN;            // loader lanes: 8 or 52

    __shared__ short Ahi[2][KSTEPS * 512];     // [parity][frag order]
    __shared__ short Alo[2][KSTEPS * 512];

    const int tid  = threadIdx.x;
    const int wave = tid >> 6;
    const int lane = tid & 63;
    const int quad = lane >> 4;
    const int lrow = lane & 15;
    const int b0   = blockIdx.x * 4;

    const int tA = (wave < 6) ? wave : 12;
    const int tB = wave + 6;                   // valid only for wave<6

    // ---- B fragments (hi/lo) + bias in VGPRs (proven layout) -------------
    short8 BH[2][KSTEPS], BL[2][KSTEPS];
    float  biasv[2];
    #pragma unroll
    for (int ti = 0; ti < 2; ++ti) {
        const int  nt    = ti ? tB : tA;
        const bool valid = (ti == 0) || (wave < 6);
        const int  np    = nt * 16 + lrow;     // permuted row r' = 4j+g
        const int  j     = np >> 2;
        const int  g     = np & 3;
        const bool jb    = valid && (j < HH);
        biasv[ti] = jb ? (bih[g * HH + j] + bhh[g * HH + j]) : 0.0f;
        #pragma unroll
        for (int ks = 0; ks < KSTEPS; ++ks) {
            #pragma unroll
            for (int jj = 0; jj < 8; ++jj) {
                const int k = ks * 32 + quad * 8 + jj;
                float wv = 0.0f;
                if (jb) {
                    const int r = g * HH + j;
                    if (k < HH)                       wv = Whh[r * HH + k];
                    else if (k >= XO && k < KTOT)     wv = Wih[r * DIN + (k - XO)];
                }
                short h_, l_;
                bf16split(wv, h_, l_);
                BH[ti][ks][jj] = h_;
                BL[ti][ks][jj] = l_;
            }
        }
    }

    // ---- EW constants (in-layout): lane = gate g of cell j, samples q*4+r -
    const int   g   = lane & 3;
    const float sA  = (g == 2) ? 2.0f : 1.0f;  // tanh = 2*sig(2x)-1
    const float sB  = (g == 2) ? 2.0f : 1.0f;
    const float sC  = (g == 2) ? -1.0f : 0.0f;
    const bool  gb0 = (g & 1) != 0;
    const bool  gb1 = (g & 2) != 0;
    const int   jA  = tA * 4 + (lrow >> 2);    // <= 51 (pad cells for tile 12)
    const int   jB  = tB * 4 + (lrow >> 2);    // < 49 when wave<6
    const int   mS  = quad * 4 + g;            // this lane's sample row
    const int   whA = addr2B(mS, jA);
    const int   whB = addr2B(mS, (wave < 6) ? jB : 0);
    const bool  stA = (quad == 0) && (jA < HH);
    const bool  stB = (quad == 0) && (wave < 6);
    float* hpA = hout + ((size_t)(b0 + g) * TT) * HH + (jA < HH ? jA : 0);
    float* hpB = hout + ((size_t)(b0 + g) * TT) * HH + ((wave < 6) ? jB : 0);
    float ccA[4] = {0, 0, 0, 0};
    float ccB[4] = {0, 0, 0, 0};

    // ---- loader role: wave 6, 4 guarded scalar loads per lane ------------
    const bool isld = (wave == 6) && (lane < NL);
    const int  ls   = lane / QN;               // sample 0..3
    const int  lq   = lane - ls * QN;          // k-quad
    const int  c0   = 4 * lq;                  // first x column of this quad
    const float* gxb = xin + ((size_t)(b0 + ls) * TT) * DIN;  // row base
    const int  ast  = addr2B(ls, XO + c0);

    auto ldx = [&](int tt, float* dst) {       // guarded, in-bounds, any align
        #pragma unroll
        for (int e = 0; e < 4; ++e)
            dst[e] = (c0 + e < DIN) ? gxb[(size_t)tt * DIN + c0 + e] : 0.0f;
    };
    auto stage = [&](const float* xv, int par) {
        short h0, l0, h1, l1, h2, l2, h3, l3;
        bf16split(xv[0], h0, l0);
        bf16split(xv[1], h1, l1);
        bf16split(xv[2], h2, l2);
        bf16split(xv[3], h3, l3);
        short4v vh = {h0, h1, h2, h3};
        short4v vl = {l0, l1, l2, l3};
        *(short4v*)&Ahi[par][ast] = vh;
        *(short4v*)&Alo[par][ast] = vl;
    };

    // ---- init: zero both parities of both planes -------------------------
    for (int i = tid; i < KSTEPS * 512; i += 448) {   // dwords = all shorts
        ((unsigned*)Ahi)[i] = 0u;
        ((unsigned*)Alo)[i] = 0u;
    }
    __syncthreads();

    // pre-stage x_0; preload x_1 -> xr1, x_2 -> xr0
    float xr0[4] = {0, 0, 0, 0}, xr1[4] = {0, 0, 0, 0};
    if (isld) {
        float x0[4];
        ldx(0, x0);
        stage(x0, 0);
        ldx(1, xr1);
        ldx(2, xr0);
    }
    __syncthreads();

    for (int t = 0; t < TT; ++t) {
        const int p = t & 1;

        // stage x_{t+1} -> A[p^1]; issue load x_{t+3} into the freed slot
        if (isld) {
            if (t + 1 < TT) {
                stage(((t + 1) & 1) ? xr1 : xr0, p ^ 1);
                if (t + 3 < TT) {
                    if ((t + 1) & 1) ldx(t + 3, xr1);
                    else             ldx(t + 3, xr0);
                }
            }
        }

        // A fragments (parity p), conflict-free b128
        short8 AH[KSTEPS], AL[KSTEPS];
        #pragma unroll
        for (int ks = 0; ks < KSTEPS; ++ks) {
            AH[ks] = *(const short8*)&Ahi[p][ks * 512 + lane * 8];
            AL[ks] = *(const short8*)&Alo[p][ks * 512 + lane * 8];
        }

        // ---- tile A: two independent chains, then add --------------------
        f32x4 Ca = {biasv[0], biasv[0], biasv[0], biasv[0]};
        f32x4 Cb = {0.f, 0.f, 0.f, 0.f};
        #pragma unroll
        for (int ks = 0; ks < KSTEPS; ++ks) {
            f32x4& C = (ks < (KSTEPS + 1) / 2) ? Ca : Cb;
            C = __builtin_amdgcn_mfma_f32_16x16x32_bf16(AH[ks], BH[0][ks], C, 0, 0, 0);
            C = __builtin_amdgcn_mfma_f32_16x16x32_bf16(AL[ks], BH[0][ks], C, 0, 0, 0);
            C = __builtin_amdgcn_mfma_f32_16x16x32_bf16(AH[ks], BL[0][ks], C, 0, 0, 0);
        }
        f32x4 C0 = Ca + Cb;

        // ---- tile B (waves 0..5) -----------------------------------------
        f32x4 C1;
        if (wave < 6) {
            f32x4 Da = {biasv[1], biasv[1], biasv[1], biasv[1]};
            f32x4 Db = {0.f, 0.f, 0.f, 0.f};
            #pragma unroll
            for (int ks = 0; ks < KSTEPS; ++ks) {
                f32x4& D = (ks < (KSTEPS + 1) / 2) ? Da : Db;
                D = __builtin_amdgcn_mfma_f32_16x16x32_bf16(AH[ks], BH[1][ks], D, 0, 0, 0);
                D = __builtin_amdgcn_mfma_f32_16x16x32_bf16(AL[ks], BH[1][ks], D, 0, 0, 0);
                D = __builtin_amdgcn_mfma_f32_16x16x32_bf16(AH[ks], BL[1][ks], D, 0, 0, 0);
            }
            C1 = Da + Db;
        }

        // ---- EW tile A in MFMA layout ------------------------------------
        {
            float y[4], iv[4], fv[4], gv[4], ov[4], hv[4];
            #pragma unroll
            for (int r = 0; r < 4; ++r) {
                const float u = fsig(sA * C0[r]);
                y[r] = fmaf(sB, u, sC);
            }
            #pragma unroll
            for (int r = 0; r < 4; ++r) {
                iv[r] = qbcast<0x00>(y[r]);
                fv[r] = qbcast<0x55>(y[r]);
                gv[r] = qbcast<0xAA>(y[r]);
                ov[r] = qbcast<0xFF>(y[r]);
            }
            #pragma unroll
            for (int r = 0; r < 4; ++r) {
                ccA[r] = fmaf(fv[r], ccA[r], iv[r] * gv[r]);
                const float th = fmaf(2.0f, fsig(2.0f * ccA[r]), -1.0f);
                hv[r] = ov[r] * th;
            }
            const float s01  = gb0 ? hv[1] : hv[0];
            const float s23  = gb0 ? hv[3] : hv[2];
            const float hsel = gb1 ? s23 : s01;
            short hh, hl;
            bf16split(hsel, hh, hl);
            Ahi[p ^ 1][whA] = hh;
            Alo[p ^ 1][whA] = hl;
            if (stA) hpA[(size_t)t * HH] = hsel;
        }

        // ---- EW tile B ---------------------------------------------------
        if (wave < 6) {
            float y[4], iv[4], fv[4], gv[4], ov[4], hv[4];
            #pragma unroll
            for (int r = 0; r < 4; ++r) {
                const float u = fsig(sA * C1[r]);
                y[r] = fmaf(sB, u, sC);
            }
            #pragma unroll
            for (int r = 0; r < 4; ++r) {
                iv[r] = qbcast<0x00>(y[r]);
                fv[r] = qbcast<0x55>(y[r]);
                gv[r] = qbcast<0xAA>(y[r]);
                ov[r] = qbcast<0xFF>(y[r]);
            }
            #pragma unroll
            for (int r = 0; r < 4; ++r) {
                ccB[r] = fmaf(fv[r], ccB[r], iv[r] * gv[r]);
                const float th = fmaf(2.0f, fsig(2.0f * ccB[r]), -1.0f);
                hv[r] = ov[r] * th;
            }
            const float s01  = gb0 ? hv[1] : hv[0];
            const float s23  = gb0 ? hv[3] : hv[2];
            const float hsel = gb1 ? s23 : s01;
            short hh, hl;
            bf16split(hsel, hh, hl);
            Ahi[p ^ 1][whB] = hh;
            Alo[p ^ 1][whB] = hl;
            if (stB) hpB[(size_t)t * HH] = hsel;
        }

        WGBAR();   // lgkm-only: A[p^1] (h + staged x) visible to all waves
    }
}

__global__ __launch_bounds__(256)
void fc_kernel(const float* __restrict__ hbuf,  // [B,T,49]
               const float* __restrict__ fcw,   // [7,49]
               const float* __restrict__ fcb,   // [7]
               float* __restrict__ outp)        // [B,T,7]
{
    constexpr int HP = 52;
    __shared__ float w[7][HP];
    __shared__ float bsh[8];
    const int tid = threadIdx.x;
    for (int i = tid; i < 7 * HP; i += 256) {
        const int o = i / HP, k = i - o * HP;
        w[o][k] = (k < HH) ? fcw[o * HH + k] : 0.0f;
    }
    if (tid < 7) bsh[tid] = fcb[tid];
    __syncthreads();

    const size_t i = (size_t)blockIdx.x * 256 + tid;   // flat (b*T + t)
    float acc[7];
    #pragma unroll
    for (int j = 0; j < 7; ++j) acc[j] = bsh[j];
    const float* hp = hbuf + i * HH;
    #pragma unroll
    for (int k = 0; k < HH; ++k) {
        const float hv = hp[k];
        #pragma unroll
        for (int j = 0; j < 7; ++j) acc[j] = fmaf(hv, w[j][k], acc[j]);
    }
    #pragma unroll
    for (int j = 0; j < 7; ++j) outp[i * 7 + j] = acc[j];
}

extern "C" void kernel_launch(void* const* d_in, const int* in_sizes, int n_in,
                              void* d_out, int out_size, void* d_ws, size_t ws_size,
                              hipStream_t stream)
{
    const float* x    = (const float*)d_in[0];   // [B,T,7]
    const float* Wih0 = (const float*)d_in[1];   // [196,7]
    const float* Wihr = (const float*)d_in[2];   // [6,196,49]
    const float* Whh  = (const float*)d_in[3];   // [7,196,49]
    const float* bih  = (const float*)d_in[4];   // [7,196]
    const float* bhh  = (const float*)d_in[5];   // [7,196]
    const float* fcw  = (const float*)d_in[6];   // [7,49]
    const float* fcb  = (const float*)d_in[7];   // [7]
    float* outp = (float*)d_out;                 // [B,T,7]
    float* hbuf = (float*)d_ws;                  // [B,T,49] fp32 = 102.8 MB

    lstm_ql<7><<<BB / 4, 448, 0, stream>>>(x, hbuf, Wih0, Whh, bih, bhh);
    for (int l = 1; l < 7; ++l) {
        lstm_ql<49><<<BB / 4, 448, 0, stream>>>(
            hbuf, hbuf,
            Wihr + (size_t)(l - 1) * GG * HH,
            Whh  + (size_t)l * GG * HH,
            bih  + (size_t)l * GG,
            bhh  + (size_t)l * GG);
    }
    fc_kernel<<<(BB * TT) / 256, 256, 0, stream>>>(hbuf, fcw, fcb, outp);
}